// Round 12
// baseline (273.176 us; speedup 1.0000x reference)
//
#include <hip/hip_runtime.h>
#include <hip/hip_bf16.h>

typedef __bf16 bf16x8 __attribute__((ext_vector_type(8)));
typedef __bf16 bf16x4 __attribute__((ext_vector_type(4)));
typedef float  f32x4  __attribute__((ext_vector_type(4)));
typedef float  f32x16 __attribute__((ext_vector_type(16)));

constexpr int N_  = 8;
constexpr int TO_ = 1024;
constexpr int TI_ = 4096;
constexpr int H_  = 512;

// ---------------------------------------------------------------------------
// helpers
// ---------------------------------------------------------------------------
__device__ inline void split8(const float4& x0, const float4& x1,
                              bf16x8& h, bf16x8& l)
{
    float xs[8] = {x0.x, x0.y, x0.z, x0.w, x1.x, x1.y, x1.z, x1.w};
#pragma unroll
    for (int i = 0; i < 8; ++i) {
        __bf16 hh = (__bf16)xs[i];
        h[i] = hh;
        l[i] = (__bf16)(xs[i] - (float)hh);
    }
}

// ---------------------------------------------------------------------------
// P1: fp32 -> (hi, lo) bf16 split (used for Q)
// ---------------------------------------------------------------------------
__global__ __launch_bounds__(256)
void split_kernel(const float* __restrict__ X, __bf16* __restrict__ Xh,
                  __bf16* __restrict__ Xl)
{
    const size_t idx = ((size_t)blockIdx.x * 256 + threadIdx.x) * 8;
    const float4* src = reinterpret_cast<const float4*>(X + idx);
    float4 x0 = src[0], x1 = src[1];
    bf16x8 h, l;
    split8(x0, x1, h, l);
    *reinterpret_cast<bf16x8*>(Xh + idx) = h;
    *reinterpret_cast<bf16x8*>(Xl + idx) = l;
}

// ---------------------------------------------------------------------------
// P1b v2 (proven R9-R11): fused V split + transpose, ONE read of V.
// ---------------------------------------------------------------------------
__global__ __launch_bounds__(256)
void splitv2_kernel(const float* __restrict__ V, __bf16* __restrict__ Vh,
                    __bf16* __restrict__ Vl, __bf16* __restrict__ Vt)
{
    __shared__ __bf16 Lh[64][72];

    const int tt = blockIdx.x, hb = blockIdx.y, n = blockIdx.z;
    const int t0 = tt * 64, h0 = hb * 64;
    const float* Vn = V + (size_t)n * TI_ * H_;
    __bf16* Vhn = Vh + (size_t)n * TI_ * H_;
    __bf16* Vln = Vl + (size_t)n * TI_ * H_;
    __bf16* Vtn = Vt + (size_t)n * H_ * TI_;

    const int tr = threadIdx.x >> 4;
    const int hc = (threadIdx.x & 15) * 4;

#pragma unroll
    for (int j = 0; j < 4; ++j) {
        const int t = tr + j * 16;
        const size_t o = (size_t)(t0 + t) * H_ + h0 + hc;
        float4 x = *reinterpret_cast<const float4*>(Vn + o);
        bf16x4 hv, lv;
        float xs[4] = {x.x, x.y, x.z, x.w};
#pragma unroll
        for (int e = 0; e < 4; ++e) {
            __bf16 hh = (__bf16)xs[e];
            hv[e] = hh;
            lv[e] = (__bf16)(xs[e] - (float)hh);
        }
        *reinterpret_cast<bf16x4*>(Vhn + o) = hv;
        *reinterpret_cast<bf16x4*>(Vln + o) = lv;
        *reinterpret_cast<bf16x4*>(&Lh[t][hc]) = hv;
    }
    __syncthreads();

    const int th = threadIdx.x >> 2;
    const int tq = threadIdx.x & 3;
#pragma unroll
    for (int s = 0; s < 2; ++s) {
        const int tb = tq * 16 + s * 8;
        bf16x8 o;
#pragma unroll
        for (int e = 0; e < 8; ++e) o[e] = Lh[tb + e][th];
        *reinterpret_cast<bf16x8*>(&Vtn[(size_t)(h0 + th) * TI_ + t0 + tb]) = o;
    }
}

// ---------------------------------------------------------------------------
// K1 v32: qk3 shell (proven 91 us) with 32x32x16 MFMA (13% faster pipe).
// Tile 128x128, BK=64, single-buffer 64 KiB, 2 blocks/CU, same XOR swizzle.
// Wave tile 64x64 = 2x2 frags of 32x32. Operand: row=lane&31,
// k=(lane>>5)*8+e. C/D: col=lane&31, row=(reg&3)+8*(reg>>2)+4*(lane>>5).
// ---------------------------------------------------------------------------
__global__ __launch_bounds__(256, 2)
void qk32_kernel(const __bf16* __restrict__ Qh, const __bf16* __restrict__ Ql,
                 const __bf16* __restrict__ Vh, const __bf16* __restrict__ Vl,
                 float* __restrict__ S)
{
    __shared__ __bf16 Ah[128 * 64];
    __shared__ __bf16 Al[128 * 64];
    __shared__ __bf16 Bh[128 * 64];
    __shared__ __bf16 Bl[128 * 64];

    const int tt = blockIdx.x, mt = blockIdx.y, n = blockIdx.z;
    const size_t qoff = ((size_t)n * TO_ + (size_t)mt * 128) * H_;
    const size_t voff = ((size_t)n * TI_ + (size_t)tt * 128) * H_;
    const __bf16* Qhb = Qh + qoff;
    const __bf16* Qlb = Ql + qoff;
    const __bf16* Vhb = Vh + voff;
    const __bf16* Vlb = Vl + voff;

    const int tid  = threadIdx.x;
    const int lane = tid & 63, wave = tid >> 6;
    const int wr = wave >> 1, wc = wave & 1;
    const int fr32 = lane & 31, kh = lane >> 5;

    const int srow = tid >> 3;
    const int sc   = tid & 7;

    auto stage = [&](const __bf16* __restrict__ g, __bf16* lds, int k0) {
#pragma unroll
        for (int i = 0; i < 4; ++i) {
            const int row = i * 32 + srow;
            const int csw = sc ^ (row & 7);
            const __bf16* gs = g + (size_t)row * H_ + k0 + csw * 8;
            const int q0 = (i * 256 + wave * 64) * 16;
            __builtin_amdgcn_global_load_lds(
                (const __attribute__((address_space(1))) void*)gs,
                (__attribute__((address_space(3))) void*)((char*)lds + q0),
                16, 0, 0);
        }
    };

    f32x16 acc[2][2] = {};

    for (int kt = 0; kt < H_ / 64; ++kt) {
        const int k0 = kt * 64;
        __syncthreads();
        stage(Qhb, Ah, k0);
        stage(Qlb, Al, k0);
        stage(Vhb, Bh, k0);
        stage(Vlb, Bl, k0);
        __syncthreads();

#pragma unroll
        for (int ks = 0; ks < 4; ++ks) {
            bf16x8 ah[2], al[2], bh[2], bl[2];
#pragma unroll
            for (int m = 0; m < 2; ++m) {
                const int row = wr * 64 + m * 32 + fr32;
                const int cs  = (ks * 2 + kh) ^ (row & 7);
                ah[m] = *reinterpret_cast<const bf16x8*>(&Ah[row * 64 + cs * 8]);
                al[m] = *reinterpret_cast<const bf16x8*>(&Al[row * 64 + cs * 8]);
            }
#pragma unroll
            for (int j = 0; j < 2; ++j) {
                const int row = wc * 64 + j * 32 + fr32;
                const int cs  = (ks * 2 + kh) ^ (row & 7);
                bh[j] = *reinterpret_cast<const bf16x8*>(&Bh[row * 64 + cs * 8]);
                bl[j] = *reinterpret_cast<const bf16x8*>(&Bl[row * 64 + cs * 8]);
            }
#pragma unroll
            for (int m = 0; m < 2; ++m)
#pragma unroll
                for (int j = 0; j < 2; ++j) {
                    acc[m][j] = __builtin_amdgcn_mfma_f32_32x32x16_bf16(ah[m], bh[j], acc[m][j], 0, 0, 0);
                    acc[m][j] = __builtin_amdgcn_mfma_f32_32x32x16_bf16(ah[m], bl[j], acc[m][j], 0, 0, 0);
                    acc[m][j] = __builtin_amdgcn_mfma_f32_32x32x16_bf16(al[m], bh[j], acc[m][j], 0, 0, 0);
                }
        }
    }

    float* Sb = S + ((size_t)n * TO_ + (size_t)mt * 128) * TI_ + (size_t)tt * 128;
#pragma unroll
    for (int m = 0; m < 2; ++m)
#pragma unroll
        for (int j = 0; j < 2; ++j) {
            const int col = wc * 64 + j * 32 + fr32;
#pragma unroll
            for (int r = 0; r < 16; ++r) {
                const int row = wr * 64 + m * 32 + (r & 3) + 8 * (r >> 2) + 4 * kh;
                Sb[(size_t)row * TI_ + col] = acc[m][j][r];
            }
        }
}

// ---------------------------------------------------------------------------
// K2 v2: in-place row softmax + bf16 copy of attn into ws (A16).
// ---------------------------------------------------------------------------
__global__ __launch_bounds__(256)
void softmax2_kernel(float* __restrict__ S, __bf16* __restrict__ A16)
{
    const int wave = threadIdx.x >> 6, lane = threadIdx.x & 63;
    const size_t row = (size_t)blockIdx.x * 4 + wave;
    float4* p = reinterpret_cast<float4*>(S + row * TI_);
    __bf16* p16 = A16 + row * TI_;

    float4 v[16];
    float m = -3.0e38f;
#pragma unroll
    for (int j = 0; j < 16; ++j) {
        v[j] = p[j * 64 + lane];
        m = fmaxf(m, fmaxf(fmaxf(v[j].x, v[j].y), fmaxf(v[j].z, v[j].w)));
    }
#pragma unroll
    for (int s = 32; s > 0; s >>= 1) m = fmaxf(m, __shfl_xor(m, s));

    constexpr float L2E = 1.4426950408889634f;
    float sum = 0.f;
#pragma unroll
    for (int j = 0; j < 16; ++j) {
        v[j].x = exp2f((v[j].x - m) * L2E);
        v[j].y = exp2f((v[j].y - m) * L2E);
        v[j].z = exp2f((v[j].z - m) * L2E);
        v[j].w = exp2f((v[j].w - m) * L2E);
        sum += (v[j].x + v[j].y) + (v[j].z + v[j].w);
    }
#pragma unroll
    for (int s = 32; s > 0; s >>= 1) sum += __shfl_xor(sum, s);

    const float inv = 1.0f / sum;
#pragma unroll
    for (int j = 0; j < 16; ++j) {
        v[j].x *= inv; v[j].y *= inv; v[j].z *= inv; v[j].w *= inv;
        p[j * 64 + lane] = v[j];
        bf16x4 o;
        o[0] = (__bf16)v[j].x; o[1] = (__bf16)v[j].y;
        o[2] = (__bf16)v[j].z; o[3] = (__bf16)v[j].w;
        *reinterpret_cast<bf16x4*>(&p16[(j * 64 + lane) * 4]) = o;
    }
}

// ---------------------------------------------------------------------------
// K3 v8b: out = attnbf16 @ Vt^T, full K (no split, no add, no Ppart).
// BM=64, BN=256, BK=64. 512 thr / 8 waves (wave 32m x 64h), dbuf LDS
// 80 KiB, grid 256 (16mt x 2ht x 8n; flat&7==n pins Vt[n] per XCD).
// ---------------------------------------------------------------------------
__global__ __launch_bounds__(512, 2)
void pv8b_kernel(const __bf16* __restrict__ A16, const __bf16* __restrict__ Vt,
                 float* __restrict__ O)
{
    __shared__ __bf16 AsmA[64 * 64],  AsmB[64 * 64];    //  8 KiB each
    __shared__ __bf16 BsmA[256 * 64], BsmB[256 * 64];   // 32 KiB each

    const int flat = blockIdx.x;
    const int n  = flat & 7;
    const int r  = flat >> 3;       // 0..31
    const int mt = r >> 1;          // 0..15
    const int ht = r & 1;           // 0..1

    const __bf16* Ab = A16 + ((size_t)n * TO_ + (size_t)mt * 64) * TI_;
    const __bf16* Bb = Vt  + ((size_t)n * H_  + (size_t)ht * 256) * TI_;

    const int tid = threadIdx.x, lane = tid & 63, wave = tid >> 6;
    const int wm = wave >> 2, wh = wave & 3;     // wave tile 32(m) x 64(h)
    const int fr = lane & 15, fq = lane >> 4;

    auto stage = [&](__bf16* asm_, __bf16* bsm_, int k0) {
        {   // A: 512 chunks, 1 issue
            const int row = tid >> 3, c = tid & 7;
            const int csw = c ^ (row & 7);
            const __bf16* gs = Ab + (size_t)row * TI_ + k0 + csw * 8;
            const int q0 = (wave * 64) * 16;
            __builtin_amdgcn_global_load_lds(
                (const __attribute__((address_space(1))) void*)gs,
                (__attribute__((address_space(3))) void*)((char*)asm_ + q0),
                16, 0, 0);
        }
#pragma unroll
        for (int i = 0; i < 4; ++i) {            // B: 2048 chunks
            const int q   = i * 512 + tid;
            const int row = q >> 3, c = q & 7;
            const int csw = c ^ (row & 7);
            const __bf16* gs = Bb + (size_t)row * TI_ + k0 + csw * 8;
            const int q0 = (i * 512 + wave * 64) * 16;
            __builtin_amdgcn_global_load_lds(
                (const __attribute__((address_space(1))) void*)gs,
                (__attribute__((address_space(3))) void*)((char*)bsm_ + q0),
                16, 0, 0);
        }
    };

    f32x4 acc[2][4] = {};

    auto compute = [&](const __bf16* Asm, const __bf16* Bsm) {
#pragma unroll
        for (int kk = 0; kk < 2; ++kk) {
            bf16x8 a[2], b[4];
#pragma unroll
            for (int m = 0; m < 2; ++m) {
                const int row = wm * 32 + m * 16 + fr;
                const int cs  = (kk * 4 + fq) ^ (row & 7);
                a[m] = *reinterpret_cast<const bf16x8*>(&Asm[row * 64 + cs * 8]);
            }
#pragma unroll
            for (int j = 0; j < 4; ++j) {
                const int row = wh * 64 + j * 16 + fr;
                const int cs  = (kk * 4 + fq) ^ (row & 7);
                b[j] = *reinterpret_cast<const bf16x8*>(&Bsm[row * 64 + cs * 8]);
            }
#pragma unroll
            for (int m = 0; m < 2; ++m)
#pragma unroll
                for (int j = 0; j < 4; ++j)
                    acc[m][j] = __builtin_amdgcn_mfma_f32_16x16x32_bf16(
                        a[m], b[j], acc[m][j], 0, 0, 0);
        }
    };

    constexpr int NT = TI_ / 64;   // 64 (even)
    stage(AsmA, BsmA, 0);
    __syncthreads();
    for (int kt = 0; kt < NT; kt += 2) {
        if (kt + 1 < NT) stage(AsmB, BsmB, (kt + 1) * 64);
        compute(AsmA, BsmA);
        __syncthreads();
        if (kt + 2 < NT) stage(AsmA, BsmA, (kt + 2) * 64);
        compute(AsmB, BsmB);
        __syncthreads();
    }

    float* Ob = O + ((size_t)n * TO_ + (size_t)mt * 64) * H_ + ht * 256;
#pragma unroll
    for (int m = 0; m < 2; ++m) {
        const int orow = wm * 32 + m * 16 + fq * 4;
#pragma unroll
        for (int j = 0; j < 4; ++j) {
            const int ocol = wh * 64 + j * 16 + fr;
#pragma unroll
            for (int r2 = 0; r2 < 4; ++r2)
                Ob[(size_t)(orow + r2) * H_ + ocol] = acc[m][j][r2];
        }
    }
}

// ===========================================================================
// Fallback tier kernels (ws >= 32 MiB only).
// ===========================================================================
constexpr int BM1 = 128, BN1 = 128, BK1 = 32, LP1 = BK1 + 8;

__global__ __launch_bounds__(256, 2)
void qk_kernel(const float* __restrict__ Q, const float* __restrict__ V,
               float* __restrict__ S)
{
    __shared__ __bf16 Ah[BM1 * LP1];
    __shared__ __bf16 Al[BM1 * LP1];
    __shared__ __bf16 Bh[BN1 * LP1];
    __shared__ __bf16 Bl[BN1 * LP1];

    const int tt = blockIdx.x, mt = blockIdx.y, n = blockIdx.z;
    const float* Qb = Q + ((size_t)n * TO_ + (size_t)mt * BM1) * H_;
    const float* Vb = V + ((size_t)n * TI_ + (size_t)tt * BN1) * H_;

    const int tid  = threadIdx.x;
    const int lane = tid & 63, wave = tid >> 6;
    const int wr = wave >> 1, wc = wave & 1;
    const int srow = tid >> 2, scg = tid & 3;

    f32x4 acc[4][4] = {};

    for (int k0 = 0; k0 < H_; k0 += BK1) {
        __syncthreads();
#pragma unroll
        for (int half = 0; half < 2; ++half) {
            const int r = srow + half * 64;
            {
                const float4* src =
                    reinterpret_cast<const float4*>(Qb + (size_t)r * H_ + k0 + scg * 8);
                float4 x0 = src[0], x1 = src[1];
                bf16x8 hv, lv;
                split8(x0, x1, hv, lv);
                *reinterpret_cast<bf16x8*>(&Ah[r * LP1 + scg * 8]) = hv;
                *reinterpret_cast<bf16x8*>(&Al[r * LP1 + scg * 8]) = lv;
            }
            {
                const float4* src =
                    reinterpret_cast<const float4*>(Vb + (size_t)r * H_ + k0 + scg * 8);
                float4 x0 = src[0], x1 = src[1];
                bf16x8 hv, lv;
                split8(x0, x1, hv, lv);
                *reinterpret_cast<bf16x8*>(&Bh[r * LP1 + scg * 8]) = hv;
                *reinterpret_cast<bf16x8*>(&Bl[r * LP1 + scg * 8]) = lv;
            }
        }
        __syncthreads();

        bf16x8 ah[4], al[4], bh[4], bl[4];
        const int fr = lane & 15, fg = (lane >> 4) * 8;
#pragma unroll
        for (int m = 0; m < 4; ++m) {
            const int row = wr * 64 + m * 16 + fr;
            ah[m] = *reinterpret_cast<const bf16x8*>(&Ah[row * LP1 + fg]);
            al[m] = *reinterpret_cast<const bf16x8*>(&Al[row * LP1 + fg]);
        }
#pragma unroll
        for (int j = 0; j < 4; ++j) {
            const int row = wc * 64 + j * 16 + fr;
            bh[j] = *reinterpret_cast<const bf16x8*>(&Bh[row * LP1 + fg]);
            bl[j] = *reinterpret_cast<const bf16x8*>(&Bl[row * LP1 + fg]);
        }
#pragma unroll
        for (int m = 0; m < 4; ++m)
#pragma unroll
            for (int j = 0; j < 4; ++j) {
                acc[m][j] = __builtin_amdgcn_mfma_f32_16x16x32_bf16(ah[m], bh[j], acc[m][j], 0, 0, 0);
                acc[m][j] = __builtin_amdgcn_mfma_f32_16x16x32_bf16(ah[m], bl[j], acc[m][j], 0, 0, 0);
                acc[m][j] = __builtin_amdgcn_mfma_f32_16x16x32_bf16(al[m], bh[j], acc[m][j], 0, 0, 0);
            }
    }

    float* Sb = S + ((size_t)n * TO_ + (size_t)mt * BM1) * TI_ + (size_t)tt * BN1;
    const int crow0 = wr * 64 + (lane >> 4) * 4;
    const int ccol0 = wc * 64 + (lane & 15);
#pragma unroll
    for (int m = 0; m < 4; ++m)
#pragma unroll
        for (int j = 0; j < 4; ++j)
#pragma unroll
            for (int r = 0; r < 4; ++r)
                Sb[(size_t)(crow0 + m * 16 + r) * TI_ + (ccol0 + j * 16)] = acc[m][j][r];
}

__global__ __launch_bounds__(256)
void softmax_kernel(float* __restrict__ S)
{
    const int wave = threadIdx.x >> 6, lane = threadIdx.x & 63;
    const size_t row = (size_t)blockIdx.x * 4 + wave;
    float4* p = reinterpret_cast<float4*>(S + row * TI_);

    float4 v[16];
    float m = -3.0e38f;
#pragma unroll
    for (int j = 0; j < 16; ++j) {
        v[j] = p[j * 64 + lane];
        m = fmaxf(m, fmaxf(fmaxf(v[j].x, v[j].y), fmaxf(v[j].z, v[j].w)));
    }
#pragma unroll
    for (int s = 32; s > 0; s >>= 1) m = fmaxf(m, __shfl_xor(m, s));

    constexpr float L2E = 1.4426950408889634f;
    float sum = 0.f;
#pragma unroll
    for (int j = 0; j < 16; ++j) {
        v[j].x = exp2f((v[j].x - m) * L2E);
        v[j].y = exp2f((v[j].y - m) * L2E);
        v[j].z = exp2f((v[j].z - m) * L2E);
        v[j].w = exp2f((v[j].w - m) * L2E);
        sum += (v[j].x + v[j].y) + (v[j].z + v[j].w);
    }
#pragma unroll
    for (int s = 32; s > 0; s >>= 1) sum += __shfl_xor(sum, s);

    const float inv = 1.0f / sum;
#pragma unroll
    for (int j = 0; j < 16; ++j) {
        v[j].x *= inv; v[j].y *= inv; v[j].z *= inv; v[j].w *= inv;
        p[j * 64 + lane] = v[j];
    }
}

__global__ __launch_bounds__(256)
void vt_kernel(const float* __restrict__ V, __bf16* __restrict__ Vt)
{
    const int hb = blockIdx.x, tb = blockIdx.y, n = blockIdx.z;
    const int h  = hb * 64 + (threadIdx.x >> 2);
    const int tq = threadIdx.x & 3;
    const float* Vn = V + (size_t)n * TI_ * H_;
    __bf16* Vtn = Vt + (size_t)n * H_ * TI_;

#pragma unroll
    for (int j = 0; j < 16; ++j) {
        const int t0 = tb * 512 + tq * 128 + j * 8;
        bf16x8 o;
#pragma unroll
        for (int e = 0; e < 8; ++e)
            o[e] = (__bf16)Vn[(size_t)(t0 + e) * H_ + h];
        *reinterpret_cast<bf16x8*>(&Vtn[(size_t)h * TI_ + t0]) = o;
    }
}

constexpr int PBM = 32, PBK = 64, PLP = PBK + 8;

__global__ __launch_bounds__(512, 2)
void pv_fast_kernel(const float* __restrict__ A, const __bf16* __restrict__ Vt,
                    float* __restrict__ O)
{
    __shared__ __bf16 AsmF[PBM * PLP];
    __shared__ __bf16 BsmF[512 * PLP];

    const int n = blockIdx.x, mt = blockIdx.y;
    const float*  Ab = A  + ((size_t)n * TO_ + (size_t)mt * PBM) * TI_;
    const __bf16* Vb = Vt + (size_t)n * H_ * TI_;

    const int tid = threadIdx.x, lane = tid & 63, wv = tid >> 6;
    const int ar = tid >> 4;
    const int ac = (tid & 15) * 4;
    const int bh = tid >> 3;
    const int bc = (tid & 7) * 8;

    float4 aReg;
    bf16x8 bReg[8];

    auto loadTile = [&](int k0) {
        aReg = *reinterpret_cast<const float4*>(Ab + (size_t)ar * TI_ + k0 + ac);
#pragma unroll
        for (int i = 0; i < 8; ++i)
            bReg[i] = *reinterpret_cast<const bf16x8*>(
                Vb + (size_t)(bh + i * 64) * TI_ + k0 + bc);
    };

    f32x4 acc[2][4] = {};
    const int fr = lane & 15, fg = (lane >> 4) * 8;

    loadTile(0);
    constexpr int NT = TI_ / PBK;
    for (int kt = 0; kt < NT; ++kt) {
        __syncthreads();
        {
            bf16x4 av;
            av[0] = (__bf16)aReg.x; av[1] = (__bf16)aReg.y;
            av[2] = (__bf16)aReg.z; av[3] = (__bf16)aReg.w;
            *reinterpret_cast<bf16x4*>(&AsmF[ar * PLP + ac]) = av;
#pragma unroll
            for (int i = 0; i < 8; ++i)
                *reinterpret_cast<bf16x8*>(&BsmF[(bh + i * 64) * PLP + bc]) = bReg[i];
        }
        __syncthreads();
        if (kt + 1 < NT) loadTile((kt + 1) * PBK);

#pragma unroll
        for (int kk = 0; kk < 2; ++kk) {
            bf16x8 af[2], bfr[4];
#pragma unroll
            for (int m = 0; m < 2; ++m)
                af[m] = *reinterpret_cast<const bf16x8*>(
                    &AsmF[(m * 16 + fr) * PLP + kk * 32 + fg]);
#pragma unroll
            for (int j = 0; j < 4; ++j)
                bfr[j] = *reinterpret_cast<const bf16x8*>(
                    &BsmF[(wv * 64 + j * 16 + fr) * PLP + kk * 32 + fg]);
#pragma unroll
            for (int m = 0; m < 2; ++m)
#pragma unroll
                for (int j = 0; j < 4; ++j)
                    acc[m][j] = __builtin_amdgcn_mfma_f32_16x16x32_bf16(
                        af[m], bfr[j], acc[m][j], 0, 0, 0);
        }
    }

    float* Ob = O + ((size_t)n * TO_ + (size_t)mt * PBM) * H_ + wv * 64;
    const int crow = (lane >> 4) * 4;
    const int ccol = lane & 15;
#pragma unroll
    for (int m = 0; m < 2; ++m)
#pragma unroll
        for (int j = 0; j < 4; ++j)
#pragma unroll
            for (int r = 0; r < 4; ++r)
                Ob[(size_t)(m * 16 + crow + r) * H_ + j * 16 + ccol] = acc[m][j][r];
}

// ---------------------------------------------------------------------------
extern "C" void kernel_launch(void* const* d_in, const int* in_sizes, int n_in,
                              void* d_out, int out_size, void* d_ws, size_t ws_size,
                              hipStream_t stream)
{
    const float* Q = (const float*)d_in[0];
    const float* V = (const float*)d_in[1];
    float* out  = (float*)d_out;
    float* attn = out + (size_t)N_ * TO_ * H_;

    const size_t NV = (size_t)N_ * TI_ * H_;
    const size_t NQ = (size_t)N_ * TO_ * H_;
    const size_t FULL_BYTES = (3 * NV + 2 * NQ) * sizeof(__bf16);
    const size_t VT_BYTES   = NV * sizeof(__bf16);

    __bf16* wsb = (__bf16*)d_ws;
    __bf16* Vt = wsb;
    __bf16* Vh = wsb + NV;
    __bf16* Vl = wsb + 2 * NV;
    __bf16* Qh = wsb + 3 * NV;
    __bf16* Ql = wsb + 3 * NV + NQ;
    __bf16* A16 = wsb + NV;                    // overlays Vh+Vl (dead after qk)

    if (ws_size >= FULL_BYTES) {
        splitv2_kernel<<<dim3(TI_ / 64, H_ / 64, N_), 256, 0, stream>>>(V, Vh, Vl, Vt);
        split_kernel<<<dim3(NQ / (256 * 8)), 256, 0, stream>>>(Q, Qh, Ql);
        qk32_kernel<<<dim3(TI_ / 128, TO_ / 128, N_), 256, 0, stream>>>(Qh, Ql, Vh, Vl, attn);
        softmax2_kernel<<<dim3(N_ * TO_ / 4), 256, 0, stream>>>(attn, A16);
        pv8b_kernel<<<dim3(256), 512, 0, stream>>>(A16, Vt, out);
    } else if (ws_size >= VT_BYTES) {
        vt_kernel<<<dim3(H_ / 64, TI_ / 512, N_), 256, 0, stream>>>(V, Vt);
        qk_kernel<<<dim3(TI_ / BN1, TO_ / BM1, N_), 256, 0, stream>>>(Q, V, attn);
        softmax_kernel<<<dim3(N_ * TO_ / 4), 256, 0, stream>>>(attn);
        pv_fast_kernel<<<dim3(N_, TO_ / PBM), 512, 0, stream>>>(attn, Vt, out);
    }
}

// Round 13
// 248.957 us; speedup vs baseline: 1.0973x; 1.0973x over previous
//
#include <hip/hip_runtime.h>
#include <hip/hip_bf16.h>

typedef __bf16 bf16x8 __attribute__((ext_vector_type(8)));
typedef __bf16 bf16x4 __attribute__((ext_vector_type(4)));
typedef float  f32x4  __attribute__((ext_vector_type(4)));

constexpr int N_  = 8;
constexpr int TO_ = 1024;
constexpr int TI_ = 4096;
constexpr int H_  = 512;

// ---------------------------------------------------------------------------
// helpers
// ---------------------------------------------------------------------------
__device__ inline void split8(const float4& x0, const float4& x1,
                              bf16x8& h, bf16x8& l)
{
    float xs[8] = {x0.x, x0.y, x0.z, x0.w, x1.x, x1.y, x1.z, x1.w};
#pragma unroll
    for (int i = 0; i < 8; ++i) {
        __bf16 hh = (__bf16)xs[i];
        h[i] = hh;
        l[i] = (__bf16)(xs[i] - (float)hh);
    }
}

// ---------------------------------------------------------------------------
// P1: fp32 -> (hi, lo) bf16 split (used for Q)
// ---------------------------------------------------------------------------
__global__ __launch_bounds__(256)
void split_kernel(const float* __restrict__ X, __bf16* __restrict__ Xh,
                  __bf16* __restrict__ Xl)
{
    const size_t idx = ((size_t)blockIdx.x * 256 + threadIdx.x) * 8;
    const float4* src = reinterpret_cast<const float4*>(X + idx);
    float4 x0 = src[0], x1 = src[1];
    bf16x8 h, l;
    split8(x0, x1, h, l);
    *reinterpret_cast<bf16x8*>(Xh + idx) = h;
    *reinterpret_cast<bf16x8*>(Xl + idx) = l;
}

// ---------------------------------------------------------------------------
// P1b v2 (proven R9-R11): fused V split + transpose, ONE read of V.
// 64t x 64h tile; coalesced reads AND coalesced Vh/Vl writes; Vt via
// padded LDS-tile transpose.
// ---------------------------------------------------------------------------
__global__ __launch_bounds__(256)
void splitv2_kernel(const float* __restrict__ V, __bf16* __restrict__ Vh,
                    __bf16* __restrict__ Vl, __bf16* __restrict__ Vt)
{
    __shared__ __bf16 Lh[64][72];

    const int tt = blockIdx.x, hb = blockIdx.y, n = blockIdx.z;
    const int t0 = tt * 64, h0 = hb * 64;
    const float* Vn = V + (size_t)n * TI_ * H_;
    __bf16* Vhn = Vh + (size_t)n * TI_ * H_;
    __bf16* Vln = Vl + (size_t)n * TI_ * H_;
    __bf16* Vtn = Vt + (size_t)n * H_ * TI_;

    const int tr = threadIdx.x >> 4;
    const int hc = (threadIdx.x & 15) * 4;

#pragma unroll
    for (int j = 0; j < 4; ++j) {
        const int t = tr + j * 16;
        const size_t o = (size_t)(t0 + t) * H_ + h0 + hc;
        float4 x = *reinterpret_cast<const float4*>(Vn + o);
        bf16x4 hv, lv;
        float xs[4] = {x.x, x.y, x.z, x.w};
#pragma unroll
        for (int e = 0; e < 4; ++e) {
            __bf16 hh = (__bf16)xs[e];
            hv[e] = hh;
            lv[e] = (__bf16)(xs[e] - (float)hh);
        }
        *reinterpret_cast<bf16x4*>(Vhn + o) = hv;
        *reinterpret_cast<bf16x4*>(Vln + o) = lv;
        *reinterpret_cast<bf16x4*>(&Lh[t][hc]) = hv;
    }
    __syncthreads();

    const int th = threadIdx.x >> 2;
    const int tq = threadIdx.x & 3;
#pragma unroll
    for (int s = 0; s < 2; ++s) {
        const int tb = tq * 16 + s * 8;
        bf16x8 o;
#pragma unroll
        for (int e = 0; e < 8; ++e) o[e] = Lh[tb + e][th];
        *reinterpret_cast<bf16x8*>(&Vtn[(size_t)(h0 + th) * TI_ + t0 + tb]) = o;
    }
}

// ---------------------------------------------------------------------------
// K1 v3 (proven R5/R7/R8/R11 @ 91 us, MfmaUtil 50%, conflicts 0):
// S = Qsplit . Vsplit^T. Tile 128x128, BK=64, single-buffer 64 KiB,
// 2 blocks/CU (inter-block stage/compute overlap), global_load_lds(16B)
// with XOR-chunk swizzle on the global source address, swizzled ds_read.
// NOTE (R12): 16x16x32 fragments span only 16 rows -> 2-way bank alias
// (free). 32x32x16 spans 32 rows -> 4-way conflict (8.4e6 cycles, -20%).
// Keep 16x16x32.
// ---------------------------------------------------------------------------
__global__ __launch_bounds__(256, 2)
void qk3_kernel(const __bf16* __restrict__ Qh, const __bf16* __restrict__ Ql,
                const __bf16* __restrict__ Vh, const __bf16* __restrict__ Vl,
                float* __restrict__ S)
{
    __shared__ __bf16 Ah[128 * 64];
    __shared__ __bf16 Al[128 * 64];
    __shared__ __bf16 Bh[128 * 64];
    __shared__ __bf16 Bl[128 * 64];

    const int tt = blockIdx.x, mt = blockIdx.y, n = blockIdx.z;
    const size_t qoff = ((size_t)n * TO_ + (size_t)mt * 128) * H_;
    const size_t voff = ((size_t)n * TI_ + (size_t)tt * 128) * H_;
    const __bf16* Qhb = Qh + qoff;
    const __bf16* Qlb = Ql + qoff;
    const __bf16* Vhb = Vh + voff;
    const __bf16* Vlb = Vl + voff;

    const int tid  = threadIdx.x;
    const int lane = tid & 63, wave = tid >> 6;
    const int wr = wave >> 1, wc = wave & 1;
    const int fr = lane & 15, fq = lane >> 4;

    const int srow = tid >> 3;
    const int sc   = tid & 7;

    auto stage = [&](const __bf16* __restrict__ g, __bf16* lds, int k0) {
#pragma unroll
        for (int i = 0; i < 4; ++i) {
            const int row = i * 32 + srow;
            const int csw = sc ^ (row & 7);
            const __bf16* gs = g + (size_t)row * H_ + k0 + csw * 8;
            const int q0 = (i * 256 + wave * 64) * 16;
            __builtin_amdgcn_global_load_lds(
                (const __attribute__((address_space(1))) void*)gs,
                (__attribute__((address_space(3))) void*)((char*)lds + q0),
                16, 0, 0);
        }
    };

    f32x4 acc[4][4] = {};

    for (int kt = 0; kt < H_ / 64; ++kt) {
        const int k0 = kt * 64;
        __syncthreads();
        stage(Qhb, Ah, k0);
        stage(Qlb, Al, k0);
        stage(Vhb, Bh, k0);
        stage(Vlb, Bl, k0);
        __syncthreads();

#pragma unroll
        for (int kk = 0; kk < 2; ++kk) {
            bf16x8 ah[4], al[4], bh[4], bl[4];
#pragma unroll
            for (int m = 0; m < 4; ++m) {
                const int row = wr * 64 + m * 16 + fr;
                const int cs  = (kk * 4 + fq) ^ (row & 7);
                ah[m] = *reinterpret_cast<const bf16x8*>(&Ah[row * 64 + cs * 8]);
                al[m] = *reinterpret_cast<const bf16x8*>(&Al[row * 64 + cs * 8]);
            }
#pragma unroll
            for (int j = 0; j < 4; ++j) {
                const int row = wc * 64 + j * 16 + fr;
                const int cs  = (kk * 4 + fq) ^ (row & 7);
                bh[j] = *reinterpret_cast<const bf16x8*>(&Bh[row * 64 + cs * 8]);
                bl[j] = *reinterpret_cast<const bf16x8*>(&Bl[row * 64 + cs * 8]);
            }
#pragma unroll
            for (int m = 0; m < 4; ++m)
#pragma unroll
                for (int j = 0; j < 4; ++j) {
                    acc[m][j] = __builtin_amdgcn_mfma_f32_16x16x32_bf16(ah[m], bh[j], acc[m][j], 0, 0, 0);
                    acc[m][j] = __builtin_amdgcn_mfma_f32_16x16x32_bf16(ah[m], bl[j], acc[m][j], 0, 0, 0);
                    acc[m][j] = __builtin_amdgcn_mfma_f32_16x16x32_bf16(al[m], bh[j], acc[m][j], 0, 0, 0);
                }
        }
    }

    float* Sb = S + ((size_t)n * TO_ + (size_t)mt * 128) * TI_ + (size_t)tt * 128;
    const int crow0 = wr * 64 + fq * 4;
    const int ccol0 = wc * 64 + fr;
#pragma unroll
    for (int m = 0; m < 4; ++m)
#pragma unroll
        for (int j = 0; j < 4; ++j)
#pragma unroll
            for (int r = 0; r < 4; ++r)
                Sb[(size_t)(crow0 + m * 16 + r) * TI_ + (ccol0 + j * 16)] = acc[m][j][r];
}

// ---------------------------------------------------------------------------
// K2 v2: in-place row softmax + bf16 copy of attn into ws (A16).
// ---------------------------------------------------------------------------
__global__ __launch_bounds__(256)
void softmax2_kernel(float* __restrict__ S, __bf16* __restrict__ A16)
{
    const int wave = threadIdx.x >> 6, lane = threadIdx.x & 63;
    const size_t row = (size_t)blockIdx.x * 4 + wave;
    float4* p = reinterpret_cast<float4*>(S + row * TI_);
    __bf16* p16 = A16 + row * TI_;

    float4 v[16];
    float m = -3.0e38f;
#pragma unroll
    for (int j = 0; j < 16; ++j) {
        v[j] = p[j * 64 + lane];
        m = fmaxf(m, fmaxf(fmaxf(v[j].x, v[j].y), fmaxf(v[j].z, v[j].w)));
    }
#pragma unroll
    for (int s = 32; s > 0; s >>= 1) m = fmaxf(m, __shfl_xor(m, s));

    constexpr float L2E = 1.4426950408889634f;
    float sum = 0.f;
#pragma unroll
    for (int j = 0; j < 16; ++j) {
        v[j].x = exp2f((v[j].x - m) * L2E);
        v[j].y = exp2f((v[j].y - m) * L2E);
        v[j].z = exp2f((v[j].z - m) * L2E);
        v[j].w = exp2f((v[j].w - m) * L2E);
        sum += (v[j].x + v[j].y) + (v[j].z + v[j].w);
    }
#pragma unroll
    for (int s = 32; s > 0; s >>= 1) sum += __shfl_xor(sum, s);

    const float inv = 1.0f / sum;
#pragma unroll
    for (int j = 0; j < 16; ++j) {
        v[j].x *= inv; v[j].y *= inv; v[j].z *= inv; v[j].w *= inv;
        p[j * 64 + lane] = v[j];
        bf16x4 o;
        o[0] = (__bf16)v[j].x; o[1] = (__bf16)v[j].y;
        o[2] = (__bf16)v[j].z; o[3] = (__bf16)v[j].w;
        *reinterpret_cast<bf16x4*>(&p16[(j * 64 + lane) * 4]) = o;
    }
}

// ---------------------------------------------------------------------------
// K3 v7 (proven R6/R8/R11): out = attnbf16 @ Vt^T, 2-way K-split, no atomics.
// BM=128, BN=256, BK=64, KC=2048. 512 thr / 8 waves, dbuf LDS, grid 256.
// ---------------------------------------------------------------------------
__global__ __launch_bounds__(512, 2)
void pv7_kernel(const __bf16* __restrict__ A16, const __bf16* __restrict__ Vt,
                float* __restrict__ O, float* __restrict__ P)
{
    __shared__ __bf16 AsmA[128 * 64], AsmB[128 * 64];
    __shared__ __bf16 BsmA[256 * 64], BsmB[256 * 64];

    const int flat = blockIdx.x;
    const int mt = flat >> 5;
    const int g  = flat & 31;
    const int n  = g >> 2;
    const int ht = (g >> 1) & 1;
    const int kc = g & 1;

    const __bf16* Ab = A16 + ((size_t)n * TO_ + (size_t)mt * 128) * TI_ + (size_t)kc * 2048;
    const __bf16* Bb = Vt  + ((size_t)n * H_  + (size_t)ht * 256) * TI_ + (size_t)kc * 2048;

    const int tid = threadIdx.x, lane = tid & 63, wave = tid >> 6;
    const int wm = wave >> 2, wh = wave & 3;
    const int fr = lane & 15, fq = lane >> 4;

    auto stage = [&](__bf16* asm_, __bf16* bsm_, int k0) {
#pragma unroll
        for (int i = 0; i < 2; ++i) {
            const int q   = i * 512 + tid;
            const int row = q >> 3, c = q & 7;
            const int csw = c ^ (row & 7);
            const __bf16* gs = Ab + (size_t)row * TI_ + k0 + csw * 8;
            const int q0 = (i * 512 + wave * 64) * 16;
            __builtin_amdgcn_global_load_lds(
                (const __attribute__((address_space(1))) void*)gs,
                (__attribute__((address_space(3))) void*)((char*)asm_ + q0),
                16, 0, 0);
        }
#pragma unroll
        for (int i = 0; i < 4; ++i) {
            const int q   = i * 512 + tid;
            const int row = q >> 3, c = q & 7;
            const int csw = c ^ (row & 7);
            const __bf16* gs = Bb + (size_t)row * TI_ + k0 + csw * 8;
            const int q0 = (i * 512 + wave * 64) * 16;
            __builtin_amdgcn_global_load_lds(
                (const __attribute__((address_space(1))) void*)gs,
                (__attribute__((address_space(3))) void*)((char*)bsm_ + q0),
                16, 0, 0);
        }
    };

    f32x4 acc[4][4] = {};

    auto compute = [&](const __bf16* Asm, const __bf16* Bsm) {
#pragma unroll
        for (int kk = 0; kk < 2; ++kk) {
            bf16x8 a[4], b[4];
#pragma unroll
            for (int m = 0; m < 4; ++m) {
                const int row = wm * 64 + m * 16 + fr;
                const int cs  = (kk * 4 + fq) ^ (row & 7);
                a[m] = *reinterpret_cast<const bf16x8*>(&Asm[row * 64 + cs * 8]);
            }
#pragma unroll
            for (int j = 0; j < 4; ++j) {
                const int row = wh * 64 + j * 16 + fr;
                const int cs  = (kk * 4 + fq) ^ (row & 7);
                b[j] = *reinterpret_cast<const bf16x8*>(&Bsm[row * 64 + cs * 8]);
            }
#pragma unroll
            for (int m = 0; m < 4; ++m)
#pragma unroll
                for (int j = 0; j < 4; ++j)
                    acc[m][j] = __builtin_amdgcn_mfma_f32_16x16x32_bf16(
                        a[m], b[j], acc[m][j], 0, 0, 0);
        }
    };

    constexpr int NT = 2048 / 64;
    stage(AsmA, BsmA, 0);
    __syncthreads();
    for (int kt = 0; kt < NT; kt += 2) {
        if (kt + 1 < NT) stage(AsmB, BsmB, (kt + 1) * 64);
        compute(AsmA, BsmA);
        __syncthreads();
        if (kt + 2 < NT) stage(AsmA, BsmA, (kt + 2) * 64);
        compute(AsmB, BsmB);
        __syncthreads();
    }

    float* D  = (kc == 0) ? O : P;
    float* Db = D + ((size_t)n * TO_ + (size_t)mt * 128) * H_ + ht * 256;
#pragma unroll
    for (int m = 0; m < 4; ++m) {
        const int orow = wm * 64 + m * 16 + fq * 4;
#pragma unroll
        for (int j = 0; j < 4; ++j) {
            const int ocol = wh * 64 + j * 16 + fr;
#pragma unroll
            for (int r = 0; r < 4; ++r)
                Db[(size_t)(orow + r) * H_ + ocol] = acc[m][j][r];
        }
    }
}

// ---------------------------------------------------------------------------
// P3: out += partial
// ---------------------------------------------------------------------------
__global__ __launch_bounds__(256)
void add_kernel(float4* __restrict__ o, const float4* __restrict__ p)
{
    const size_t i = (size_t)blockIdx.x * 256 + threadIdx.x;
    float4 a = o[i], b = p[i];
    a.x += b.x; a.y += b.y; a.z += b.z; a.w += b.w;
    o[i] = a;
}

// ===========================================================================
// Fallback tier kernels (ws >= 32 MiB only).
// ===========================================================================
constexpr int BM1 = 128, BN1 = 128, BK1 = 32, LP1 = BK1 + 8;

__global__ __launch_bounds__(256, 2)
void qk_kernel(const float* __restrict__ Q, const float* __restrict__ V,
               float* __restrict__ S)
{
    __shared__ __bf16 Ah[BM1 * LP1];
    __shared__ __bf16 Al[BM1 * LP1];
    __shared__ __bf16 Bh[BN1 * LP1];
    __shared__ __bf16 Bl[BN1 * LP1];

    const int tt = blockIdx.x, mt = blockIdx.y, n = blockIdx.z;
    const float* Qb = Q + ((size_t)n * TO_ + (size_t)mt * BM1) * H_;
    const float* Vb = V + ((size_t)n * TI_ + (size_t)tt * BN1) * H_;

    const int tid  = threadIdx.x;
    const int lane = tid & 63, wave = tid >> 6;
    const int wr = wave >> 1, wc = wave & 1;
    const int srow = tid >> 2, scg = tid & 3;

    f32x4 acc[4][4] = {};

    for (int k0 = 0; k0 < H_; k0 += BK1) {
        __syncthreads();
#pragma unroll
        for (int half = 0; half < 2; ++half) {
            const int r = srow + half * 64;
            {
                const float4* src =
                    reinterpret_cast<const float4*>(Qb + (size_t)r * H_ + k0 + scg * 8);
                float4 x0 = src[0], x1 = src[1];
                bf16x8 hv, lv;
                split8(x0, x1, hv, lv);
                *reinterpret_cast<bf16x8*>(&Ah[r * LP1 + scg * 8]) = hv;
                *reinterpret_cast<bf16x8*>(&Al[r * LP1 + scg * 8]) = lv;
            }
            {
                const float4* src =
                    reinterpret_cast<const float4*>(Vb + (size_t)r * H_ + k0 + scg * 8);
                float4 x0 = src[0], x1 = src[1];
                bf16x8 hv, lv;
                split8(x0, x1, hv, lv);
                *reinterpret_cast<bf16x8*>(&Bh[r * LP1 + scg * 8]) = hv;
                *reinterpret_cast<bf16x8*>(&Bl[r * LP1 + scg * 8]) = lv;
            }
        }
        __syncthreads();

        bf16x8 ah[4], al[4], bh[4], bl[4];
        const int fr = lane & 15, fg = (lane >> 4) * 8;
#pragma unroll
        for (int m = 0; m < 4; ++m) {
            const int row = wr * 64 + m * 16 + fr;
            ah[m] = *reinterpret_cast<const bf16x8*>(&Ah[row * LP1 + fg]);
            al[m] = *reinterpret_cast<const bf16x8*>(&Al[row * LP1 + fg]);
        }
#pragma unroll
        for (int j = 0; j < 4; ++j) {
            const int row = wc * 64 + j * 16 + fr;
            bh[j] = *reinterpret_cast<const bf16x8*>(&Bh[row * LP1 + fg]);
            bl[j] = *reinterpret_cast<const bf16x8*>(&Bl[row * LP1 + fg]);
        }
#pragma unroll
        for (int m = 0; m < 4; ++m)
#pragma unroll
            for (int j = 0; j < 4; ++j) {
                acc[m][j] = __builtin_amdgcn_mfma_f32_16x16x32_bf16(ah[m], bh[j], acc[m][j], 0, 0, 0);
                acc[m][j] = __builtin_amdgcn_mfma_f32_16x16x32_bf16(ah[m], bl[j], acc[m][j], 0, 0, 0);
                acc[m][j] = __builtin_amdgcn_mfma_f32_16x16x32_bf16(al[m], bh[j], acc[m][j], 0, 0, 0);
            }
    }

    float* Sb = S + ((size_t)n * TO_ + (size_t)mt * BM1) * TI_ + (size_t)tt * BN1;
    const int crow0 = wr * 64 + (lane >> 4) * 4;
    const int ccol0 = wc * 64 + (lane & 15);
#pragma unroll
    for (int m = 0; m < 4; ++m)
#pragma unroll
        for (int j = 0; j < 4; ++j)
#pragma unroll
            for (int r = 0; r < 4; ++r)
                Sb[(size_t)(crow0 + m * 16 + r) * TI_ + (ccol0 + j * 16)] = acc[m][j][r];
}

__global__ __launch_bounds__(256)
void softmax_kernel(float* __restrict__ S)
{
    const int wave = threadIdx.x >> 6, lane = threadIdx.x & 63;
    const size_t row = (size_t)blockIdx.x * 4 + wave;
    float4* p = reinterpret_cast<float4*>(S + row * TI_);

    float4 v[16];
    float m = -3.0e38f;
#pragma unroll
    for (int j = 0; j < 16; ++j) {
        v[j] = p[j * 64 + lane];
        m = fmaxf(m, fmaxf(fmaxf(v[j].x, v[j].y), fmaxf(v[j].z, v[j].w)));
    }
#pragma unroll
    for (int s = 32; s > 0; s >>= 1) m = fmaxf(m, __shfl_xor(m, s));

    constexpr float L2E = 1.4426950408889634f;
    float sum = 0.f;
#pragma unroll
    for (int j = 0; j < 16; ++j) {
        v[j].x = exp2f((v[j].x - m) * L2E);
        v[j].y = exp2f((v[j].y - m) * L2E);
        v[j].z = exp2f((v[j].z - m) * L2E);
        v[j].w = exp2f((v[j].w - m) * L2E);
        sum += (v[j].x + v[j].y) + (v[j].z + v[j].w);
    }
#pragma unroll
    for (int s = 32; s > 0; s >>= 1) sum += __shfl_xor(sum, s);

    const float inv = 1.0f / sum;
#pragma unroll
    for (int j = 0; j < 16; ++j) {
        v[j].x *= inv; v[j].y *= inv; v[j].z *= inv; v[j].w *= inv;
        p[j * 64 + lane] = v[j];
    }
}

__global__ __launch_bounds__(256)
void vt_kernel(const float* __restrict__ V, __bf16* __restrict__ Vt)
{
    const int hb = blockIdx.x, tb = blockIdx.y, n = blockIdx.z;
    const int h  = hb * 64 + (threadIdx.x >> 2);
    const int tq = threadIdx.x & 3;
    const float* Vn = V + (size_t)n * TI_ * H_;
    __bf16* Vtn = Vt + (size_t)n * H_ * TI_;

#pragma unroll
    for (int j = 0; j < 16; ++j) {
        const int t0 = tb * 512 + tq * 128 + j * 8;
        bf16x8 o;
#pragma unroll
        for (int e = 0; e < 8; ++e)
            o[e] = (__bf16)Vn[(size_t)(t0 + e) * H_ + h];
        *reinterpret_cast<bf16x8*>(&Vtn[(size_t)h * TI_ + t0]) = o;
    }
}

constexpr int PBM = 32, PBK = 64, PLP = PBK + 8;

__global__ __launch_bounds__(512, 2)
void pv_fast_kernel(const float* __restrict__ A, const __bf16* __restrict__ Vt,
                    float* __restrict__ O)
{
    __shared__ __bf16 AsmF[PBM * PLP];
    __shared__ __bf16 BsmF[512 * PLP];

    const int n = blockIdx.x, mt = blockIdx.y;
    const float*  Ab = A  + ((size_t)n * TO_ + (size_t)mt * PBM) * TI_;
    const __bf16* Vb = Vt + (size_t)n * H_ * TI_;

    const int tid = threadIdx.x, lane = tid & 63, wv = tid >> 6;
    const int ar = tid >> 4;
    const int ac = (tid & 15) * 4;
    const int bh = tid >> 3;
    const int bc = (tid & 7) * 8;

    float4 aReg;
    bf16x8 bReg[8];

    auto loadTile = [&](int k0) {
        aReg = *reinterpret_cast<const float4*>(Ab + (size_t)ar * TI_ + k0 + ac);
#pragma unroll
        for (int i = 0; i < 8; ++i)
            bReg[i] = *reinterpret_cast<const bf16x8*>(
                Vb + (size_t)(bh + i * 64) * TI_ + k0 + bc);
    };

    f32x4 acc[2][4] = {};
    const int fr = lane & 15, fg = (lane >> 4) * 8;

    loadTile(0);
    constexpr int NT = TI_ / PBK;
    for (int kt = 0; kt < NT; ++kt) {
        __syncthreads();
        {
            bf16x4 av;
            av[0] = (__bf16)aReg.x; av[1] = (__bf16)aReg.y;
            av[2] = (__bf16)aReg.z; av[3] = (__bf16)aReg.w;
            *reinterpret_cast<bf16x4*>(&AsmF[ar * PLP + ac]) = av;
#pragma unroll
            for (int i = 0; i < 8; ++i)
                *reinterpret_cast<bf16x8*>(&BsmF[(bh + i * 64) * PLP + bc]) = bReg[i];
        }
        __syncthreads();
        if (kt + 1 < NT) loadTile((kt + 1) * PBK);

#pragma unroll
        for (int kk = 0; kk < 2; ++kk) {
            bf16x8 af[2], bfr[4];
#pragma unroll
            for (int m = 0; m < 2; ++m)
                af[m] = *reinterpret_cast<const bf16x8*>(
                    &AsmF[(m * 16 + fr) * PLP + kk * 32 + fg]);
#pragma unroll
            for (int j = 0; j < 4; ++j)
                bfr[j] = *reinterpret_cast<const bf16x8*>(
                    &BsmF[(wv * 64 + j * 16 + fr) * PLP + kk * 32 + fg]);
#pragma unroll
            for (int m = 0; m < 2; ++m)
#pragma unroll
                for (int j = 0; j < 4; ++j)
                    acc[m][j] = __builtin_amdgcn_mfma_f32_16x16x32_bf16(
                        af[m], bfr[j], acc[m][j], 0, 0, 0);
        }
    }

    float* Ob = O + ((size_t)n * TO_ + (size_t)mt * PBM) * H_ + wv * 64;
    const int crow = (lane >> 4) * 4;
    const int ccol = lane & 15;
#pragma unroll
    for (int m = 0; m < 2; ++m)
#pragma unroll
        for (int j = 0; j < 4; ++j)
#pragma unroll
            for (int r = 0; r < 4; ++r)
                Ob[(size_t)(m * 16 + crow + r) * H_ + j * 16 + ccol] = acc[m][j][r];
}

// ---------------------------------------------------------------------------
extern "C" void kernel_launch(void* const* d_in, const int* in_sizes, int n_in,
                              void* d_out, int out_size, void* d_ws, size_t ws_size,
                              hipStream_t stream)
{
    const float* Q = (const float*)d_in[0];
    const float* V = (const float*)d_in[1];
    float* out  = (float*)d_out;
    float* attn = out + (size_t)N_ * TO_ * H_;

    const size_t NV = (size_t)N_ * TI_ * H_;
    const size_t NQ = (size_t)N_ * TO_ * H_;
    const size_t FULL_BYTES = (3 * NV + 2 * NQ) * sizeof(__bf16);
    const size_t VT_BYTES   = NV * sizeof(__bf16);

    __bf16* wsb = (__bf16*)d_ws;
    __bf16* Vt = wsb;
    __bf16* Vh = wsb + NV;
    __bf16* Vl = wsb + 2 * NV;
    __bf16* Qh = wsb + 3 * NV;
    __bf16* Ql = wsb + 3 * NV + NQ;
    __bf16* A16 = wsb + NV;                    // overlays Vh+Vl (dead after qk)
    float*  Ppart = (float*)(wsb + 3 * NV);    // overlays Qh+Ql (dead after qk)

    if (ws_size >= FULL_BYTES) {
        splitv2_kernel<<<dim3(TI_ / 64, H_ / 64, N_), 256, 0, stream>>>(V, Vh, Vl, Vt);
        split_kernel<<<dim3(NQ / (256 * 8)), 256, 0, stream>>>(Q, Qh, Ql);
        qk3_kernel<<<dim3(TI_ / 128, TO_ / 128, N_), 256, 0, stream>>>(Qh, Ql, Vh, Vl, attn);
        softmax2_kernel<<<dim3(N_ * TO_ / 4), 256, 0, stream>>>(attn, A16);
        pv7_kernel<<<dim3(256), 512, 0, stream>>>(A16, Vt, out, Ppart);
        add_kernel<<<dim3((unsigned)(NQ / 4 / 256)), 256, 0, stream>>>(
            (float4*)out, (const float4*)Ppart);
    } else if (ws_size >= VT_BYTES) {
        vt_kernel<<<dim3(H_ / 64, TI_ / 512, N_), 256, 0, stream>>>(V, Vt);
        qk_kernel<<<dim3(TI_ / BN1, TO_ / BM1, N_), 256, 0, stream>>>(Q, V, attn);
        softmax_kernel<<<dim3(N_ * TO_ / 4), 256, 0, stream>>>(attn);
        pv_fast_kernel<<<dim3(N_, TO_ / PBM), 512, 0, stream>>>(attn, Vt, out);
    }
}

// Round 14
// 244.927 us; speedup vs baseline: 1.1153x; 1.0165x over previous
//
#include <hip/hip_runtime.h>
#include <hip/hip_bf16.h>

typedef __bf16 bf16x8 __attribute__((ext_vector_type(8)));
typedef __bf16 bf16x4 __attribute__((ext_vector_type(4)));
typedef float  f32x4  __attribute__((ext_vector_type(4)));

constexpr int N_  = 8;
constexpr int TO_ = 1024;
constexpr int TI_ = 4096;
constexpr int H_  = 512;

// ---------------------------------------------------------------------------
// helpers
// ---------------------------------------------------------------------------
__device__ inline void split8(const float4& x0, const float4& x1,
                              bf16x8& h, bf16x8& l)
{
    float xs[8] = {x0.x, x0.y, x0.z, x0.w, x1.x, x1.y, x1.z, x1.w};
#pragma unroll
    for (int i = 0; i < 8; ++i) {
        __bf16 hh = (__bf16)xs[i];
        h[i] = hh;
        l[i] = (__bf16)(xs[i] - (float)hh);
    }
}

// ---------------------------------------------------------------------------
// P1: fp32 -> (hi, lo) bf16 split (fallback tier only)
// ---------------------------------------------------------------------------
__global__ __launch_bounds__(256)
void split_kernel(const float* __restrict__ X, __bf16* __restrict__ Xh,
                  __bf16* __restrict__ Xl)
{
    const size_t idx = ((size_t)blockIdx.x * 256 + threadIdx.x) * 8;
    const float4* src = reinterpret_cast<const float4*>(X + idx);
    float4 x0 = src[0], x1 = src[1];
    bf16x8 h, l;
    split8(x0, x1, h, l);
    *reinterpret_cast<bf16x8*>(Xh + idx) = h;
    *reinterpret_cast<bf16x8*>(Xl + idx) = l;
}

// ---------------------------------------------------------------------------
// P1b v3: fused V split+transpose (proven R9-R13) PLUS Q split folded into
// the same launch via blockIdx.z==8 (512 extra blocks, 4 iters each, no LDS,
// no barriers on that path; branch is block-uniform).
// grid (TI/64, H/64, N+1), 256 threads.
// ---------------------------------------------------------------------------
__global__ __launch_bounds__(256)
void splitv3_kernel(const float* __restrict__ V, __bf16* __restrict__ Vh,
                    __bf16* __restrict__ Vl, __bf16* __restrict__ Vt,
                    const float* __restrict__ Q, __bf16* __restrict__ Qh,
                    __bf16* __restrict__ Ql)
{
    __shared__ __bf16 Lh[64][72];

    if (blockIdx.z == N_) {
        // ---- Q split path: 512 blocks x 4 iters x 256 thr x 8 elems = 4.19M
        const int bq = blockIdx.x + 64 * blockIdx.y;   // 0..511
#pragma unroll
        for (int it = 0; it < 4; ++it) {
            const size_t idx =
                (((size_t)bq * 4 + it) * 256 + threadIdx.x) * 8;
            const float4* src = reinterpret_cast<const float4*>(Q + idx);
            float4 x0 = src[0], x1 = src[1];
            bf16x8 h, l;
            split8(x0, x1, h, l);
            *reinterpret_cast<bf16x8*>(Qh + idx) = h;
            *reinterpret_cast<bf16x8*>(Ql + idx) = l;
        }
        return;
    }

    // ---- V split + transpose path (identical to proven splitv2)
    const int tt = blockIdx.x, hb = blockIdx.y, n = blockIdx.z;
    const int t0 = tt * 64, h0 = hb * 64;
    const float* Vn = V + (size_t)n * TI_ * H_;
    __bf16* Vhn = Vh + (size_t)n * TI_ * H_;
    __bf16* Vln = Vl + (size_t)n * TI_ * H_;
    __bf16* Vtn = Vt + (size_t)n * H_ * TI_;

    const int tr = threadIdx.x >> 4;
    const int hc = (threadIdx.x & 15) * 4;

#pragma unroll
    for (int j = 0; j < 4; ++j) {
        const int t = tr + j * 16;
        const size_t o = (size_t)(t0 + t) * H_ + h0 + hc;
        float4 x = *reinterpret_cast<const float4*>(Vn + o);
        bf16x4 hv, lv;
        float xs[4] = {x.x, x.y, x.z, x.w};
#pragma unroll
        for (int e = 0; e < 4; ++e) {
            __bf16 hh = (__bf16)xs[e];
            hv[e] = hh;
            lv[e] = (__bf16)(xs[e] - (float)hh);
        }
        *reinterpret_cast<bf16x4*>(Vhn + o) = hv;
        *reinterpret_cast<bf16x4*>(Vln + o) = lv;
        *reinterpret_cast<bf16x4*>(&Lh[t][hc]) = hv;
    }
    __syncthreads();

    const int th = threadIdx.x >> 2;
    const int tq = threadIdx.x & 3;
#pragma unroll
    for (int s = 0; s < 2; ++s) {
        const int tb = tq * 16 + s * 8;
        bf16x8 o;
#pragma unroll
        for (int e = 0; e < 8; ++e) o[e] = Lh[tb + e][th];
        *reinterpret_cast<bf16x8*>(&Vtn[(size_t)(h0 + th) * TI_ + t0 + tb]) = o;
    }
}

// ---------------------------------------------------------------------------
// K1 v3 (proven R5/R7/R8/R11/R13 @ 91 us, MfmaUtil 50%, conflicts 0):
// S = Qsplit . Vsplit^T. Tile 128x128, BK=64, single-buffer 64 KiB,
// 2 blocks/CU (inter-block stage/compute overlap), global_load_lds(16B)
// with XOR-chunk swizzle on the global source address, swizzled ds_read.
// NOTE (R12): 16x16x32 fragments span only 16 rows -> 2-way bank alias
// (free). 32x32x16 spans 32 rows -> 4-way conflict. Keep 16x16x32.
// ---------------------------------------------------------------------------
__global__ __launch_bounds__(256, 2)
void qk3_kernel(const __bf16* __restrict__ Qh, const __bf16* __restrict__ Ql,
                const __bf16* __restrict__ Vh, const __bf16* __restrict__ Vl,
                float* __restrict__ S)
{
    __shared__ __bf16 Ah[128 * 64];
    __shared__ __bf16 Al[128 * 64];
    __shared__ __bf16 Bh[128 * 64];
    __shared__ __bf16 Bl[128 * 64];

    const int tt = blockIdx.x, mt = blockIdx.y, n = blockIdx.z;
    const size_t qoff = ((size_t)n * TO_ + (size_t)mt * 128) * H_;
    const size_t voff = ((size_t)n * TI_ + (size_t)tt * 128) * H_;
    const __bf16* Qhb = Qh + qoff;
    const __bf16* Qlb = Ql + qoff;
    const __bf16* Vhb = Vh + voff;
    const __bf16* Vlb = Vl + voff;

    const int tid  = threadIdx.x;
    const int lane = tid & 63, wave = tid >> 6;
    const int wr = wave >> 1, wc = wave & 1;
    const int fr = lane & 15, fq = lane >> 4;

    const int srow = tid >> 3;
    const int sc   = tid & 7;

    auto stage = [&](const __bf16* __restrict__ g, __bf16* lds, int k0) {
#pragma unroll
        for (int i = 0; i < 4; ++i) {
            const int row = i * 32 + srow;
            const int csw = sc ^ (row & 7);
            const __bf16* gs = g + (size_t)row * H_ + k0 + csw * 8;
            const int q0 = (i * 256 + wave * 64) * 16;
            __builtin_amdgcn_global_load_lds(
                (const __attribute__((address_space(1))) void*)gs,
                (__attribute__((address_space(3))) void*)((char*)lds + q0),
                16, 0, 0);
        }
    };

    f32x4 acc[4][4] = {};

    for (int kt = 0; kt < H_ / 64; ++kt) {
        const int k0 = kt * 64;
        __syncthreads();
        stage(Qhb, Ah, k0);
        stage(Qlb, Al, k0);
        stage(Vhb, Bh, k0);
        stage(Vlb, Bl, k0);
        __syncthreads();

#pragma unroll
        for (int kk = 0; kk < 2; ++kk) {
            bf16x8 ah[4], al[4], bh[4], bl[4];
#pragma unroll
            for (int m = 0; m < 4; ++m) {
                const int row = wr * 64 + m * 16 + fr;
                const int cs  = (kk * 4 + fq) ^ (row & 7);
                ah[m] = *reinterpret_cast<const bf16x8*>(&Ah[row * 64 + cs * 8]);
                al[m] = *reinterpret_cast<const bf16x8*>(&Al[row * 64 + cs * 8]);
            }
#pragma unroll
            for (int j = 0; j < 4; ++j) {
                const int row = wc * 64 + j * 16 + fr;
                const int cs  = (kk * 4 + fq) ^ (row & 7);
                bh[j] = *reinterpret_cast<const bf16x8*>(&Bh[row * 64 + cs * 8]);
                bl[j] = *reinterpret_cast<const bf16x8*>(&Bl[row * 64 + cs * 8]);
            }
#pragma unroll
            for (int m = 0; m < 4; ++m)
#pragma unroll
                for (int j = 0; j < 4; ++j) {
                    acc[m][j] = __builtin_amdgcn_mfma_f32_16x16x32_bf16(ah[m], bh[j], acc[m][j], 0, 0, 0);
                    acc[m][j] = __builtin_amdgcn_mfma_f32_16x16x32_bf16(ah[m], bl[j], acc[m][j], 0, 0, 0);
                    acc[m][j] = __builtin_amdgcn_mfma_f32_16x16x32_bf16(al[m], bh[j], acc[m][j], 0, 0, 0);
                }
        }
    }

    float* Sb = S + ((size_t)n * TO_ + (size_t)mt * 128) * TI_ + (size_t)tt * 128;
    const int crow0 = wr * 64 + fq * 4;
    const int ccol0 = wc * 64 + fr;
#pragma unroll
    for (int m = 0; m < 4; ++m)
#pragma unroll
        for (int j = 0; j < 4; ++j)
#pragma unroll
            for (int r = 0; r < 4; ++r)
                Sb[(size_t)(crow0 + m * 16 + r) * TI_ + (ccol0 + j * 16)] = acc[m][j][r];
}

// ---------------------------------------------------------------------------
// K2 v2: in-place row softmax + bf16 copy of attn into ws (A16).
// ---------------------------------------------------------------------------
__global__ __launch_bounds__(256)
void softmax2_kernel(float* __restrict__ S, __bf16* __restrict__ A16)
{
    const int wave = threadIdx.x >> 6, lane = threadIdx.x & 63;
    const size_t row = (size_t)blockIdx.x * 4 + wave;
    float4* p = reinterpret_cast<float4*>(S + row * TI_);
    __bf16* p16 = A16 + row * TI_;

    float4 v[16];
    float m = -3.0e38f;
#pragma unroll
    for (int j = 0; j < 16; ++j) {
        v[j] = p[j * 64 + lane];
        m = fmaxf(m, fmaxf(fmaxf(v[j].x, v[j].y), fmaxf(v[j].z, v[j].w)));
    }
#pragma unroll
    for (int s = 32; s > 0; s >>= 1) m = fmaxf(m, __shfl_xor(m, s));

    constexpr float L2E = 1.4426950408889634f;
    float sum = 0.f;
#pragma unroll
    for (int j = 0; j < 16; ++j) {
        v[j].x = exp2f((v[j].x - m) * L2E);
        v[j].y = exp2f((v[j].y - m) * L2E);
        v[j].z = exp2f((v[j].z - m) * L2E);
        v[j].w = exp2f((v[j].w - m) * L2E);
        sum += (v[j].x + v[j].y) + (v[j].z + v[j].w);
    }
#pragma unroll
    for (int s = 32; s > 0; s >>= 1) sum += __shfl_xor(sum, s);

    const float inv = 1.0f / sum;
#pragma unroll
    for (int j = 0; j < 16; ++j) {
        v[j].x *= inv; v[j].y *= inv; v[j].z *= inv; v[j].w *= inv;
        p[j * 64 + lane] = v[j];
        bf16x4 o;
        o[0] = (__bf16)v[j].x; o[1] = (__bf16)v[j].y;
        o[2] = (__bf16)v[j].z; o[3] = (__bf16)v[j].w;
        *reinterpret_cast<bf16x4*>(&p16[(j * 64 + lane) * 4]) = o;
    }
}

// ---------------------------------------------------------------------------
// K3 v7 (proven R6/R8/R11/R13): out = attnbf16 @ Vt^T, 2-way K-split.
// BM=128, BN=256, BK=64, KC=2048. 512 thr / 8 waves, dbuf LDS, grid 256.
// ---------------------------------------------------------------------------
__global__ __launch_bounds__(512, 2)
void pv7_kernel(const __bf16* __restrict__ A16, const __bf16* __restrict__ Vt,
                float* __restrict__ O, float* __restrict__ P)
{
    __shared__ __bf16 AsmA[128 * 64], AsmB[128 * 64];
    __shared__ __bf16 BsmA[256 * 64], BsmB[256 * 64];

    const int flat = blockIdx.x;
    const int mt = flat >> 5;
    const int g  = flat & 31;
    const int n  = g >> 2;
    const int ht = (g >> 1) & 1;
    const int kc = g & 1;

    const __bf16* Ab = A16 + ((size_t)n * TO_ + (size_t)mt * 128) * TI_ + (size_t)kc * 2048;
    const __bf16* Bb = Vt  + ((size_t)n * H_  + (size_t)ht * 256) * TI_ + (size_t)kc * 2048;

    const int tid = threadIdx.x, lane = tid & 63, wave = tid >> 6;
    const int wm = wave >> 2, wh = wave & 3;
    const int fr = lane & 15, fq = lane >> 4;

    auto stage = [&](__bf16* asm_, __bf16* bsm_, int k0) {
#pragma unroll
        for (int i = 0; i < 2; ++i) {
            const int q   = i * 512 + tid;
            const int row = q >> 3, c = q & 7;
            const int csw = c ^ (row & 7);
            const __bf16* gs = Ab + (size_t)row * TI_ + k0 + csw * 8;
            const int q0 = (i * 512 + wave * 64) * 16;
            __builtin_amdgcn_global_load_lds(
                (const __attribute__((address_space(1))) void*)gs,
                (__attribute__((address_space(3))) void*)((char*)asm_ + q0),
                16, 0, 0);
        }
#pragma unroll
        for (int i = 0; i < 4; ++i) {
            const int q   = i * 512 + tid;
            const int row = q >> 3, c = q & 7;
            const int csw = c ^ (row & 7);
            const __bf16* gs = Bb + (size_t)row * TI_ + k0 + csw * 8;
            const int q0 = (i * 512 + wave * 64) * 16;
            __builtin_amdgcn_global_load_lds(
                (const __attribute__((address_space(1))) void*)gs,
                (__attribute__((address_space(3))) void*)((char*)bsm_ + q0),
                16, 0, 0);
        }
    };

    f32x4 acc[4][4] = {};

    auto compute = [&](const __bf16* Asm, const __bf16* Bsm) {
#pragma unroll
        for (int kk = 0; kk < 2; ++kk) {
            bf16x8 a[4], b[4];
#pragma unroll
            for (int m = 0; m < 4; ++m) {
                const int row = wm * 64 + m * 16 + fr;
                const int cs  = (kk * 4 + fq) ^ (row & 7);
                a[m] = *reinterpret_cast<const bf16x8*>(&Asm[row * 64 + cs * 8]);
            }
#pragma unroll
            for (int j = 0; j < 4; ++j) {
                const int row = wh * 64 + j * 16 + fr;
                const int cs  = (kk * 4 + fq) ^ (row & 7);
                b[j] = *reinterpret_cast<const bf16x8*>(&Bsm[row * 64 + cs * 8]);
            }
#pragma unroll
            for (int m = 0; m < 4; ++m)
#pragma unroll
                for (int j = 0; j < 4; ++j)
                    acc[m][j] = __builtin_amdgcn_mfma_f32_16x16x32_bf16(
                        a[m], b[j], acc[m][j], 0, 0, 0);
        }
    };

    constexpr int NT = 2048 / 64;
    stage(AsmA, BsmA, 0);
    __syncthreads();
    for (int kt = 0; kt < NT; kt += 2) {
        if (kt + 1 < NT) stage(AsmB, BsmB, (kt + 1) * 64);
        compute(AsmA, BsmA);
        __syncthreads();
        if (kt + 2 < NT) stage(AsmA, BsmA, (kt + 2) * 64);
        compute(AsmB, BsmB);
        __syncthreads();
    }

    float* D  = (kc == 0) ? O : P;
    float* Db = D + ((size_t)n * TO_ + (size_t)mt * 128) * H_ + ht * 256;
#pragma unroll
    for (int m = 0; m < 4; ++m) {
        const int orow = wm * 64 + m * 16 + fq * 4;
#pragma unroll
        for (int j = 0; j < 4; ++j) {
            const int ocol = wh * 64 + j * 16 + fr;
#pragma unroll
            for (int r = 0; r < 4; ++r)
                Db[(size_t)(orow + r) * H_ + ocol] = acc[m][j][r];
        }
    }
}

// ---------------------------------------------------------------------------
// P3: out += partial
// ---------------------------------------------------------------------------
__global__ __launch_bounds__(256)
void add_kernel(float4* __restrict__ o, const float4* __restrict__ p)
{
    const size_t i = (size_t)blockIdx.x * 256 + threadIdx.x;
    float4 a = o[i], b = p[i];
    a.x += b.x; a.y += b.y; a.z += b.z; a.w += b.w;
    o[i] = a;
}

// ===========================================================================
// Fallback tier kernels (ws >= 32 MiB only).
// ===========================================================================
constexpr int BM1 = 128, BN1 = 128, BK1 = 32, LP1 = BK1 + 8;

__global__ __launch_bounds__(256, 2)
void qk_kernel(const float* __restrict__ Q, const float* __restrict__ V,
               float* __restrict__ S)
{
    __shared__ __bf16 Ah[BM1 * LP1];
    __shared__ __bf16 Al[BM1 * LP1];
    __shared__ __bf16 Bh[BN1 * LP1];
    __shared__ __bf16 Bl[BN1 * LP1];

    const int tt = blockIdx.x, mt = blockIdx.y, n = blockIdx.z;
    const float* Qb = Q + ((size_t)n * TO_ + (size_t)mt * BM1) * H_;
    const float* Vb = V + ((size_t)n * TI_ + (size_t)tt * BN1) * H_;

    const int tid  = threadIdx.x;
    const int lane = tid & 63, wave = tid >> 6;
    const int wr = wave >> 1, wc = wave & 1;
    const int srow = tid >> 2, scg = tid & 3;

    f32x4 acc[4][4] = {};

    for (int k0 = 0; k0 < H_; k0 += BK1) {
        __syncthreads();
#pragma unroll
        for (int half = 0; half < 2; ++half) {
            const int r = srow + half * 64;
            {
                const float4* src =
                    reinterpret_cast<const float4*>(Qb + (size_t)r * H_ + k0 + scg * 8);
                float4 x0 = src[0], x1 = src[1];
                bf16x8 hv, lv;
                split8(x0, x1, hv, lv);
                *reinterpret_cast<bf16x8*>(&Ah[r * LP1 + scg * 8]) = hv;
                *reinterpret_cast<bf16x8*>(&Al[r * LP1 + scg * 8]) = lv;
            }
            {
                const float4* src =
                    reinterpret_cast<const float4*>(Vb + (size_t)r * H_ + k0 + scg * 8);
                float4 x0 = src[0], x1 = src[1];
                bf16x8 hv, lv;
                split8(x0, x1, hv, lv);
                *reinterpret_cast<bf16x8*>(&Bh[r * LP1 + scg * 8]) = hv;
                *reinterpret_cast<bf16x8*>(&Bl[r * LP1 + scg * 8]) = lv;
            }
        }
        __syncthreads();

        bf16x8 ah[4], al[4], bh[4], bl[4];
        const int fr = lane & 15, fg = (lane >> 4) * 8;
#pragma unroll
        for (int m = 0; m < 4; ++m) {
            const int row = wr * 64 + m * 16 + fr;
            ah[m] = *reinterpret_cast<const bf16x8*>(&Ah[row * LP1 + fg]);
            al[m] = *reinterpret_cast<const bf16x8*>(&Al[row * LP1 + fg]);
        }
#pragma unroll
        for (int j = 0; j < 4; ++j) {
            const int row = wc * 64 + j * 16 + fr;
            bh[j] = *reinterpret_cast<const bf16x8*>(&Bh[row * LP1 + fg]);
            bl[j] = *reinterpret_cast<const bf16x8*>(&Bl[row * LP1 + fg]);
        }
#pragma unroll
        for (int m = 0; m < 4; ++m)
#pragma unroll
            for (int j = 0; j < 4; ++j) {
                acc[m][j] = __builtin_amdgcn_mfma_f32_16x16x32_bf16(ah[m], bh[j], acc[m][j], 0, 0, 0);
                acc[m][j] = __builtin_amdgcn_mfma_f32_16x16x32_bf16(ah[m], bl[j], acc[m][j], 0, 0, 0);
                acc[m][j] = __builtin_amdgcn_mfma_f32_16x16x32_bf16(al[m], bh[j], acc[m][j], 0, 0, 0);
            }
    }

    float* Sb = S + ((size_t)n * TO_ + (size_t)mt * BM1) * TI_ + (size_t)tt * BN1;
    const int crow0 = wr * 64 + (lane >> 4) * 4;
    const int ccol0 = wc * 64 + (lane & 15);
#pragma unroll
    for (int m = 0; m < 4; ++m)
#pragma unroll
        for (int j = 0; j < 4; ++j)
#pragma unroll
            for (int r = 0; r < 4; ++r)
                Sb[(size_t)(crow0 + m * 16 + r) * TI_ + (ccol0 + j * 16)] = acc[m][j][r];
}

__global__ __launch_bounds__(256)
void softmax_kernel(float* __restrict__ S)
{
    const int wave = threadIdx.x >> 6, lane = threadIdx.x & 63;
    const size_t row = (size_t)blockIdx.x * 4 + wave;
    float4* p = reinterpret_cast<float4*>(S + row * TI_);

    float4 v[16];
    float m = -3.0e38f;
#pragma unroll
    for (int j = 0; j < 16; ++j) {
        v[j] = p[j * 64 + lane];
        m = fmaxf(m, fmaxf(fmaxf(v[j].x, v[j].y), fmaxf(v[j].z, v[j].w)));
    }
#pragma unroll
    for (int s = 32; s > 0; s >>= 1) m = fmaxf(m, __shfl_xor(m, s));

    constexpr float L2E = 1.4426950408889634f;
    float sum = 0.f;
#pragma unroll
    for (int j = 0; j < 16; ++j) {
        v[j].x = exp2f((v[j].x - m) * L2E);
        v[j].y = exp2f((v[j].y - m) * L2E);
        v[j].z = exp2f((v[j].z - m) * L2E);
        v[j].w = exp2f((v[j].w - m) * L2E);
        sum += (v[j].x + v[j].y) + (v[j].z + v[j].w);
    }
#pragma unroll
    for (int s = 32; s > 0; s >>= 1) sum += __shfl_xor(sum, s);

    const float inv = 1.0f / sum;
#pragma unroll
    for (int j = 0; j < 16; ++j) {
        v[j].x *= inv; v[j].y *= inv; v[j].z *= inv; v[j].w *= inv;
        p[j * 64 + lane] = v[j];
    }
}

__global__ __launch_bounds__(256)
void vt_kernel(const float* __restrict__ V, __bf16* __restrict__ Vt)
{
    const int hb = blockIdx.x, tb = blockIdx.y, n = blockIdx.z;
    const int h  = hb * 64 + (threadIdx.x >> 2);
    const int tq = threadIdx.x & 3;
    const float* Vn = V + (size_t)n * TI_ * H_;
    __bf16* Vtn = Vt + (size_t)n * H_ * TI_;

#pragma unroll
    for (int j = 0; j < 16; ++j) {
        const int t0 = tb * 512 + tq * 128 + j * 8;
        bf16x8 o;
#pragma unroll
        for (int e = 0; e < 8; ++e)
            o[e] = (__bf16)Vn[(size_t)(t0 + e) * H_ + h];
        *reinterpret_cast<bf16x8*>(&Vtn[(size_t)h * TI_ + t0]) = o;
    }
}

constexpr int PBM = 32, PBK = 64, PLP = PBK + 8;

__global__ __launch_bounds__(512, 2)
void pv_fast_kernel(const float* __restrict__ A, const __bf16* __restrict__ Vt,
                    float* __restrict__ O)
{
    __shared__ __bf16 AsmF[PBM * PLP];
    __shared__ __bf16 BsmF[512 * PLP];

    const int n = blockIdx.x, mt = blockIdx.y;
    const float*  Ab = A  + ((size_t)n * TO_ + (size_t)mt * PBM) * TI_;
    const __bf16* Vb = Vt + (size_t)n * H_ * TI_;

    const int tid = threadIdx.x, lane = tid & 63, wv = tid >> 6;
    const int ar = tid >> 4;
    const int ac = (tid & 15) * 4;
    const int bh = tid >> 3;
    const int bc = (tid & 7) * 8;

    float4 aReg;
    bf16x8 bReg[8];

    auto loadTile = [&](int k0) {
        aReg = *reinterpret_cast<const float4*>(Ab + (size_t)ar * TI_ + k0 + ac);
#pragma unroll
        for (int i = 0; i < 8; ++i)
            bReg[i] = *reinterpret_cast<const bf16x8*>(
                Vb + (size_t)(bh + i * 64) * TI_ + k0 + bc);
    };

    f32x4 acc[2][4] = {};
    const int fr = lane & 15, fg = (lane >> 4) * 8;

    loadTile(0);
    constexpr int NT = TI_ / PBK;
    for (int kt = 0; kt < NT; ++kt) {
        __syncthreads();
        {
            bf16x4 av;
            av[0] = (__bf16)aReg.x; av[1] = (__bf16)aReg.y;
            av[2] = (__bf16)aReg.z; av[3] = (__bf16)aReg.w;
            *reinterpret_cast<bf16x4*>(&AsmF[ar * PLP + ac]) = av;
#pragma unroll
            for (int i = 0; i < 8; ++i)
                *reinterpret_cast<bf16x8*>(&BsmF[(bh + i * 64) * PLP + bc]) = bReg[i];
        }
        __syncthreads();
        if (kt + 1 < NT) loadTile((kt + 1) * PBK);

#pragma unroll
        for (int kk = 0; kk < 2; ++kk) {
            bf16x8 af[2], bfr[4];
#pragma unroll
            for (int m = 0; m < 2; ++m)
                af[m] = *reinterpret_cast<const bf16x8*>(
                    &AsmF[(m * 16 + fr) * PLP + kk * 32 + fg]);
#pragma unroll
            for (int j = 0; j < 4; ++j)
                bfr[j] = *reinterpret_cast<const bf16x8*>(
                    &BsmF[(wv * 64 + j * 16 + fr) * PLP + kk * 32 + fg]);
#pragma unroll
            for (int m = 0; m < 2; ++m)
#pragma unroll
                for (int j = 0; j < 4; ++j)
                    acc[m][j] = __builtin_amdgcn_mfma_f32_16x16x32_bf16(
                        af[m], bfr[j], acc[m][j], 0, 0, 0);
        }
    }

    float* Ob = O + ((size_t)n * TO_ + (size_t)mt * PBM) * H_ + wv * 64;
    const int crow = (lane >> 4) * 4;
    const int ccol = lane & 15;
#pragma unroll
    for (int m = 0; m < 2; ++m)
#pragma unroll
        for (int j = 0; j < 4; ++j)
#pragma unroll
            for (int r = 0; r < 4; ++r)
                Ob[(size_t)(m * 16 + crow + r) * H_ + j * 16 + ccol] = acc[m][j][r];
}

// ---------------------------------------------------------------------------
extern "C" void kernel_launch(void* const* d_in, const int* in_sizes, int n_in,
                              void* d_out, int out_size, void* d_ws, size_t ws_size,
                              hipStream_t stream)
{
    const float* Q = (const float*)d_in[0];
    const float* V = (const float*)d_in[1];
    float* out  = (float*)d_out;
    float* attn = out + (size_t)N_ * TO_ * H_;

    const size_t NV = (size_t)N_ * TI_ * H_;
    const size_t NQ = (size_t)N_ * TO_ * H_;
    const size_t FULL_BYTES = (3 * NV + 2 * NQ) * sizeof(__bf16);
    const size_t VT_BYTES   = NV * sizeof(__bf16);

    __bf16* wsb = (__bf16*)d_ws;
    __bf16* Vt = wsb;
    __bf16* Vh = wsb + NV;
    __bf16* Vl = wsb + 2 * NV;
    __bf16* Qh = wsb + 3 * NV;
    __bf16* Ql = wsb + 3 * NV + NQ;
    __bf16* A16 = wsb + NV;                    // overlays Vh+Vl (dead after qk)
    float*  Ppart = (float*)(wsb + 3 * NV);    // overlays Qh+Ql (dead after qk)

    if (ws_size >= FULL_BYTES) {
        splitv3_kernel<<<dim3(TI_ / 64, H_ / 64, N_ + 1), 256, 0, stream>>>(
            V, Vh, Vl, Vt, Q, Qh, Ql);
        qk3_kernel<<<dim3(TI_ / 128, TO_ / 128, N_), 256, 0, stream>>>(Qh, Ql, Vh, Vl, attn);
        softmax2_kernel<<<dim3(N_ * TO_ / 4), 256, 0, stream>>>(attn, A16);
        pv7_kernel<<<dim3(256), 512, 0, stream>>>(A16, Vt, out, Ppart);
        add_kernel<<<dim3((unsigned)(NQ / 4 / 256)), 256, 0, stream>>>(
            (float4*)out, (const float4*)Ppart);
    } else if (ws_size >= VT_BYTES) {
        vt_kernel<<<dim3(H_ / 64, TI_ / 512, N_), 256, 0, stream>>>(V, Vt);
        qk_kernel<<<dim3(TI_ / BN1, TO_ / BM1, N_), 256, 0, stream>>>(Q, V, attn);
        softmax_kernel<<<dim3(N_ * TO_ / 4), 256, 0, stream>>>(attn);
        pv_fast_kernel<<<dim3(N_, TO_ / PBM), 512, 0, stream>>>(attn, Vt, out);
    }
}